// Round 10
// baseline (91.515 us; speedup 1.0000x reference)
//
#include <hip/hip_runtime.h>

// ---- problem constants ----
#define NCAM      6
#define NB        4
#define NROWS     24          // NB*NCAM
#define NQ        65536       // 256*256
#define MAXLEN_   65536

// flat f32 offsets into d_out (return order)
#define OFF_QGRID   0
#define OFF_RESTORE 3145728    // 24*65536*2
#define OFF_REFPTS  6291456    // + 4*6*256*256*2
#define OFF_COUNTS  18874368   // + 24*65536*4*2

typedef float nfloat2 __attribute__((ext_vector_type(2)));  // native vec for nt-store

// z values of the 4 pillar points, f32-linspace path
__device__ __forceinline__ float zval(int d) {
    const float z[4] = { -4.5f, -2.16666674613952637f,
                          0.166666507720947266f, 2.5f };
    return z[d];
}

__device__ __forceinline__ float clip21(float x) {
    return fminf(fmaxf(x, -2.1f), 2.1f);
}

// Projection: visibility via multiply-form (sign-exact vs division), stored
// u,v via v_rcp. Bit-identical to the round-5..8 passing versions.
__device__ __forceinline__ bool proj_point(const float m[12], float x, float y, float z,
                                           float& u, float& v) {
    float c0 = ((m[0]*x + m[1]*y) + m[2]*z) + m[3];
    float c1 = ((m[4]*x + m[5]*y) + m[6]*z) + m[7];
    float c2 = ((m[8]*x + m[9]*y) + m[10]*z) + m[11];
    float zcl = fmaxf(c2, 1e-5f);
    float inv = __builtin_amdgcn_rcpf(zcl);
    u = (c0 * inv) * (1.0f / 928.0f);   // IMW
    v = (c1 * inv) * (1.0f / 512.0f);   // IMH
    return (c2 > 1e-5f) & (c1 > 0.0f) & (c1 < 512.0f * zcl)
         & (c0 > 0.0f) & (c0 < 928.0f * zcl);
}

__device__ __forceinline__ void load_mat(const float* __restrict__ ego2img, int row, float m[12]) {
    const float* M = ego2img + row * 16;
    #pragma unroll
    for (int i = 0; i < 12; ++i) m[i] = M[i];
}

__device__ __forceinline__ void bev_xy(int qx, int qy, float& x, float& y) {
    x = ((float)qx + 0.5f) * (1.0f/256.0f) * 102.4f - 51.2f;
    y = ((float)qy + 0.5f) * (1.0f/256.0f) * 102.4f - 51.2f;
}

// ---------- kernel 1: per-256q-subchunk visible-pillar counts ----------
// grid (64, 24), 256 threads. Each wave owns 256 consecutive q -> one count.
__global__ void __launch_bounds__(256)
k_count(const float* __restrict__ ego2img, int* __restrict__ chunkCounts)
{
    int chunk = blockIdx.x, row = blockIdx.y;
    float m[12]; load_mat(ego2img, row, m);
    int t = threadIdx.x;
    int lane = t & 63;
    int q0 = chunk * 1024 + t * 4;
    int cnt = 0;
    #pragma unroll
    for (int i = 0; i < 4; ++i) {
        int q = q0 + i;
        float x, y; bev_xy(q & 255, q >> 8, x, y);
        bool va = false;
        #pragma unroll
        for (int d = 0; d < 4; ++d) {
            float u, v;
            va |= proj_point(m, x, y, zval(d), u, v);
        }
        unsigned long long bal = __ballot(va);
        if (lane == 0) cnt += __popcll(bal);
    }
    if (lane == 0)
        chunkCounts[row * 256 + chunk * 4 + (t >> 6)] = cnt;
}

// ---------- kernel 2: fused pack + restore + counts ----------
// grid (256, NB), 256 threads. Block = one BEV row (qy = blockIdx.x) of one
// batch, all 6 cameras. Projections computed ONCE (uv held in registers for
// all 6 cameras), ONE barrier before the store phase, then all global stores
// issue back-to-back with no intervening syncs.
__global__ void __launch_bounds__(256)
k_fused(const float* __restrict__ ego2img, const int* __restrict__ chunkCounts,
        float* __restrict__ out)
{
    int chunk = blockIdx.x, b = blockIdx.y;
    int t = threadIdx.x;
    int lane = t & 63, wid = t >> 6;
    unsigned long long lt = (1ull << lane) - 1ull;

    __shared__ int sBase[NCAM], sTotal[NCAM];
    __shared__ int waveCnt[NCAM][4];
    __shared__ float2 srow[NCAM][256];     // staged restore row (12 KB)

    // phase 0: per-camera exclusive prefix over the row's 256 subchunk counts
    for (int c = wid; c < NCAM; c += 4) {
        const int* p = chunkCounts + (b * NCAM + c) * 256;
        int4 v4 = ((const int4*)p)[lane];            // 4 consecutive counts
        int s = v4.x + v4.y + v4.z + v4.w;
        int incl = s;
        #pragma unroll
        for (int off = 1; off < 64; off <<= 1) {
            int n = __shfl_up(incl, off, 64);
            if (lane >= off) incl += n;
        }
        if (lane == (chunk >> 2)) {
            int base = incl - s;
            int k = chunk & 3;
            if (k > 0) base += v4.x;
            if (k > 1) base += v4.y;
            if (k > 2) base += v4.z;
            sBase[c] = base;
        }
        if (lane == 63) sTotal[c] = incl;
    }

    int q  = chunk * 256 + t;       // this block: qy == chunk, qx == t
    int qx = t, qy = chunk;
    float x, y; bev_xy(qx, qy, x, y);

    // phase A: project ALL cameras once; keep uv + ballots in registers
    float uvall[NCAM][8];
    unsigned long long bal[NCAM];
    #pragma unroll
    for (int c = 0; c < NCAM; ++c) {
        float m[12]; load_mat(ego2img, b * NCAM + c, m);
        bool vis = false;
        #pragma unroll
        for (int d = 0; d < 4; ++d) {
            float u, v;
            bool vi = proj_point(m, x, y, zval(d), u, v);
            uvall[c][2*d]   = clip21(u);
            uvall[c][2*d+1] = clip21(v);
            vis |= vi;
        }
        bal[c] = __ballot(vis);
        if (lane == 0) waveCnt[c][wid] = __popcll(bal[c]);
    }
    __syncthreads();   // the ONE barrier: waveCnt + sBase/sTotal ready

    int rnk[NCAM];     // per-thread rank (or -1) per camera

    // phase B: all-camera store burst (no barriers)
    #pragma unroll
    for (int c = 0; c < NCAM; ++c) {
        bool vis = (bal[c] >> lane) & 1ull;
        int wbase = 0;
        #pragma unroll
        for (int w = 0; w < 3; ++w) if (w < wid) wbase += waveCnt[c][w];
        int r = sBase[c] + wbase + __popcll(bal[c] & lt);

        float2* qgrid  = (float2*)(out + OFF_QGRID)  + (size_t)(b * NCAM + c) * MAXLEN_;
        float4* refpF4 = (float4*)(out + OFF_REFPTS) + (size_t)(b * NCAM + c) * (MAXLEN_ * 2);

        if (vis) {
            float2 g;
            g.x = ((float)qx / 255.0f) * 2.0f - 1.0f;
            g.y = ((float)qy / 255.0f) * 2.0f - 1.0f;
            qgrid[r] = g;
            refpF4[2*r]     = make_float4(uvall[c][0], uvall[c][1], uvall[c][2], uvall[c][3]);
            refpF4[2*r + 1] = make_float4(uvall[c][4], uvall[c][5], uvall[c][6], uvall[c][7]);
            rnk[c] = r;
        } else {
            rnk[c] = -1;
        }

        // tail fill (flat, coalesced): block owns slots [256*chunk, 256*chunk+256)
        int s0 = max(sTotal[c], chunk << 8);
        int n  = ((chunk + 1) << 8) - s0;
        if (n > 0) {
            for (int i = t; i < n; i += 256)
                qgrid[s0 + i] = make_float2(-1.5f, -1.5f);
            float4 z4 = make_float4(0.f, 0.f, 0.f, 0.f);
            for (int i = t; i < 2 * n; i += 256)
                refpF4[2*s0 + i] = z4;
        }
    }

    // phase C: stage restore row in LDS, counts, then coalesced plane writes
    int over = 0;
    #pragma unroll
    for (int c = 0; c < NCAM; ++c) {
        int r = rnk[c];
        if (r >= 0) {
            float gx = ((float)(r & 255) / 255.0f) * 2.0f - 1.0f;
            float gy = ((float)(c * 256 + (r >> 8)) / 1535.0f) * 2.0f - 1.0f;
            srow[over][t] = make_float2(gx, gy);
            ++over;
        }
    }
    for (int o = over; o < NCAM; ++o)
        srow[o][t] = make_float2(-1.5f, -1.5f);
    out[OFF_COUNTS + b * NQ + q] = 1.0f / fmaxf((float)over, 1.0f);
    __syncthreads();

    // full-line single-use stream -> nontemporal to keep L2 free for scatters
    float2* rest = (float2*)(out + OFF_RESTORE) + (size_t)b * NCAM * NQ;
    #pragma unroll
    for (int o = 0; o < NCAM; ++o) {
        float2 vsrc = srow[o][t];
        nfloat2 vv; vv.x = vsrc.x; vv.y = vsrc.y;
        __builtin_nontemporal_store(vv, (nfloat2*)&rest[(o * 256 + qy) * 256 + t]);
    }
}

extern "C" void kernel_launch(void* const* d_in, const int* in_sizes, int n_in,
                              void* d_out, int out_size, void* d_ws, size_t ws_size,
                              hipStream_t stream)
{
    const float* ego2img = (const float*)d_in[0];
    float* out = (float*)d_out;
    int* chunkCounts = (int*)d_ws;   // 24*256 ints = 24.6 KB

    k_count<<<dim3(64, NROWS), 256, 0, stream>>>(ego2img, chunkCounts);
    k_fused<<<dim3(256, NB),   256, 0, stream>>>(ego2img, chunkCounts, out);
}

// Round 11
// 89.738 us; speedup vs baseline: 1.0198x; 1.0198x over previous
//
#include <hip/hip_runtime.h>

// ---- problem constants ----
#define NCAM      6
#define NB        4
#define NROWS     24          // NB*NCAM
#define NQ        65536       // 256*256
#define MAXLEN_   65536

// flat f32 offsets into d_out (return order)
#define OFF_QGRID   0
#define OFF_RESTORE 3145728    // 24*65536*2
#define OFF_REFPTS  6291456    // + 4*6*256*256*2
#define OFF_COUNTS  18874368   // + 24*65536*4*2

// z values of the 4 pillar points, f32-linspace path
__device__ __forceinline__ float zval(int d) {
    const float z[4] = { -4.5f, -2.16666674613952637f,
                          0.166666507720947266f, 2.5f };
    return z[d];
}

__device__ __forceinline__ float clip21(float x) {
    return fminf(fmaxf(x, -2.1f), 2.1f);
}

// Projection: visibility via multiply-form (sign-exact vs division), stored
// u,v via v_rcp. Bit-identical to the round-5..8 passing versions.
__device__ __forceinline__ bool proj_point(const float m[12], float x, float y, float z,
                                           float& u, float& v) {
    float c0 = ((m[0]*x + m[1]*y) + m[2]*z) + m[3];
    float c1 = ((m[4]*x + m[5]*y) + m[6]*z) + m[7];
    float c2 = ((m[8]*x + m[9]*y) + m[10]*z) + m[11];
    float zcl = fmaxf(c2, 1e-5f);
    float inv = __builtin_amdgcn_rcpf(zcl);
    u = (c0 * inv) * (1.0f / 928.0f);   // IMW
    v = (c1 * inv) * (1.0f / 512.0f);   // IMH
    return (c2 > 1e-5f) & (c1 > 0.0f) & (c1 < 512.0f * zcl)
         & (c0 > 0.0f) & (c0 < 928.0f * zcl);
}

__device__ __forceinline__ void load_mat(const float* __restrict__ ego2img, int row, float m[12]) {
    const float* M = ego2img + row * 16;
    #pragma unroll
    for (int i = 0; i < 12; ++i) m[i] = M[i];
}

__device__ __forceinline__ void bev_xy(int qx, int qy, float& x, float& y) {
    x = ((float)qx + 0.5f) * (1.0f/256.0f) * 102.4f - 51.2f;
    y = ((float)qy + 0.5f) * (1.0f/256.0f) * 102.4f - 51.2f;
}

// ---------- kernel 1: per-256q-subchunk visible-pillar counts ----------
// grid (64, 24), 256 threads. Each wave owns 256 consecutive q -> one count.
__global__ void __launch_bounds__(256)
k_count(const float* __restrict__ ego2img, int* __restrict__ chunkCounts)
{
    int chunk = blockIdx.x, row = blockIdx.y;
    float m[12]; load_mat(ego2img, row, m);
    int t = threadIdx.x;
    int lane = t & 63;
    int q0 = chunk * 1024 + t * 4;
    int cnt = 0;
    #pragma unroll
    for (int i = 0; i < 4; ++i) {
        int q = q0 + i;
        float x, y; bev_xy(q & 255, q >> 8, x, y);
        bool va = false;
        #pragma unroll
        for (int d = 0; d < 4; ++d) {
            float u, v;
            va |= proj_point(m, x, y, zval(d), u, v);
        }
        unsigned long long bal = __ballot(va);
        if (lane == 0) cnt += __popcll(bal);
    }
    if (lane == 0)
        chunkCounts[row * 256 + chunk * 4 + (t >> 6)] = cnt;
}

// ---------- kernel 2: fused pack + restore + counts ----------
// grid (256, NB), 256 threads. Block = one BEV row (qy = blockIdx.x) of one
// batch, all 6 cameras. Projections computed ONCE per camera; one barrier per
// camera; refp stored directly (no LDS staging) as two back-to-back dwordx4
// per lane covering a contiguous packed run. (Best measured: round 8.)
__global__ void __launch_bounds__(256)
k_fused(const float* __restrict__ ego2img, const int* __restrict__ chunkCounts,
        float* __restrict__ out)
{
    int chunk = blockIdx.x, b = blockIdx.y;
    int t = threadIdx.x;
    int lane = t & 63, wid = t >> 6;
    unsigned long long lt = (1ull << lane) - 1ull;

    __shared__ int sBase[NCAM], sTotal[NCAM];
    __shared__ int waveCnt[NCAM][4];
    __shared__ float2 srow[NCAM][256];     // staged restore row (12 KB)

    // phase 0: per-camera exclusive prefix over the row's 256 subchunk counts
    for (int c = wid; c < NCAM; c += 4) {
        const int* p = chunkCounts + (b * NCAM + c) * 256;
        int4 v4 = ((const int4*)p)[lane];            // 4 consecutive counts
        int s = v4.x + v4.y + v4.z + v4.w;
        int incl = s;
        #pragma unroll
        for (int off = 1; off < 64; off <<= 1) {
            int n = __shfl_up(incl, off, 64);
            if (lane >= off) incl += n;
        }
        if (lane == (chunk >> 2)) {
            int base = incl - s;
            int k = chunk & 3;
            if (k > 0) base += v4.x;
            if (k > 1) base += v4.y;
            if (k > 2) base += v4.z;
            sBase[c] = base;
        }
        if (lane == 63) sTotal[c] = incl;
    }

    int q  = chunk * 256 + t;       // this block: qy == chunk, qx == t
    int qx = t, qy = chunk;
    float x, y; bev_xy(qx, qy, x, y);

    int rnk[NCAM];                  // per-thread rank (or -1) per camera

    // per camera: project once, ballot, barrier, rank, direct stores, tail
    #pragma unroll
    for (int c = 0; c < NCAM; ++c) {
        float m[12]; load_mat(ego2img, b * NCAM + c, m);
        float uv[8];
        bool vis = false;
        #pragma unroll
        for (int d = 0; d < 4; ++d) {
            float u, v;
            bool vi = proj_point(m, x, y, zval(d), u, v);
            uv[2*d]   = clip21(u);
            uv[2*d+1] = clip21(v);
            vis |= vi;
        }
        unsigned long long bal = __ballot(vis);
        if (lane == 0) waveCnt[c][wid] = __popcll(bal);
        __syncthreads();   // barrier c: waveCnt[c] ready (c==0 also sBase/sTotal)

        int wbase = 0;
        #pragma unroll
        for (int w = 0; w < 3; ++w) if (w < wid) wbase += waveCnt[c][w];
        int r = sBase[c] + wbase + __popcll(bal & lt);

        float2* qgrid  = (float2*)(out + OFF_QGRID)  + (size_t)(b * NCAM + c) * MAXLEN_;
        float4* refpF4 = (float4*)(out + OFF_REFPTS) + (size_t)(b * NCAM + c) * (MAXLEN_ * 2);

        if (vis) {
            float2 g;
            g.x = ((float)qx / 255.0f) * 2.0f - 1.0f;
            g.y = ((float)qy / 255.0f) * 2.0f - 1.0f;
            qgrid[r] = g;
            refpF4[2*r]     = make_float4(uv[0], uv[1], uv[2], uv[3]);
            refpF4[2*r + 1] = make_float4(uv[4], uv[5], uv[6], uv[7]);
            rnk[c] = r;
        } else {
            rnk[c] = -1;
        }

        // tail fill (flat, coalesced): block owns slots [256*chunk, 256*chunk+256)
        int s0 = max(sTotal[c], chunk << 8);
        int n  = ((chunk + 1) << 8) - s0;
        if (n > 0) {
            for (int i = t; i < n; i += 256)
                qgrid[s0 + i] = make_float2(-1.5f, -1.5f);
            float4 z4 = make_float4(0.f, 0.f, 0.f, 0.f);
            for (int i = t; i < 2 * n; i += 256)
                refpF4[2*s0 + i] = z4;
        }
    }

    // phase C: stage restore row in LDS, counts, then coalesced plane writes
    int over = 0;
    #pragma unroll
    for (int c = 0; c < NCAM; ++c) {
        int r = rnk[c];
        if (r >= 0) {
            float gx = ((float)(r & 255) / 255.0f) * 2.0f - 1.0f;
            float gy = ((float)(c * 256 + (r >> 8)) / 1535.0f) * 2.0f - 1.0f;
            srow[over][t] = make_float2(gx, gy);
            ++over;
        }
    }
    for (int o = over; o < NCAM; ++o)
        srow[o][t] = make_float2(-1.5f, -1.5f);
    out[OFF_COUNTS + b * NQ + q] = 1.0f / fmaxf((float)over, 1.0f);
    __syncthreads();

    float2* rest = (float2*)(out + OFF_RESTORE) + (size_t)b * NCAM * NQ;
    #pragma unroll
    for (int o = 0; o < NCAM; ++o)
        rest[(o * 256 + qy) * 256 + t] = srow[o][t];
}

extern "C" void kernel_launch(void* const* d_in, const int* in_sizes, int n_in,
                              void* d_out, int out_size, void* d_ws, size_t ws_size,
                              hipStream_t stream)
{
    const float* ego2img = (const float*)d_in[0];
    float* out = (float*)d_out;
    int* chunkCounts = (int*)d_ws;   // 24*256 ints = 24.6 KB

    k_count<<<dim3(64, NROWS), 256, 0, stream>>>(ego2img, chunkCounts);
    k_fused<<<dim3(256, NB),   256, 0, stream>>>(ego2img, chunkCounts, out);
}